// Round 1
// baseline (661.023 us; speedup 1.0000x reference)
//
#include <hip/hip_runtime.h>

#define NN 1024
#define MM 1022          // N-2 interior
#define BB 8
#define TOTAL_ITERS 11   // 1 explicit step + scan length 10

// Folds all scalar structure into 10 coefficients:
// coef[0..8] = mu*(k1+k2)/(mu*sum(k3))   (the combined stencil, pre-divided)
// coef[9]    = H^2/(mu*sum(k3))          (multiplier for interior f)
__global__ void coef_kernel(const float* __restrict__ mu,
                            const float* __restrict__ k1,
                            const float* __restrict__ k2,
                            const float* __restrict__ k3,
                            float* __restrict__ coef) {
    if (threadIdx.x == 0 && blockIdx.x == 0) {
        float m = mu[0];
        float s3 = 0.0f;
        for (int t = 0; t < 9; ++t) s3 += k3[t];
        float inv_d = 1.0f / (m * s3);   // y3 is the constant mu*sum(k3)
        for (int t = 0; t < 9; ++t) coef[t] = m * (k1[t] + k2[t]) * inv_d;
        const float h = 1.0f / (float)(NN - 1);
        coef[9] = h * h * inv_d;
    }
}

// One Jacobi-style step: yout = f_int*coef9 + sum_{a,b} coef[a*3+b]*ypad[i+a][j+b]
// ypad is yin zero-padded (GD=0 Dirichlet).
__global__ __launch_bounds__(256) void stencil_kernel(
        const float* __restrict__ yin,
        const float* __restrict__ f,
        const float* __restrict__ coef,
        float* __restrict__ yout) {
    const int j = blockIdx.x * blockDim.x + threadIdx.x;
    const int i = blockIdx.y;
    const int b = blockIdx.z;
    if (j >= MM) return;

    const float* yb = yin + (size_t)b * MM * MM;
    const float* fb = f + (size_t)b * NN * NN;

    float c[10];
#pragma unroll
    for (int t = 0; t < 10; ++t) c[t] = coef[t];

    float acc = fb[(size_t)(i + 1) * NN + (j + 1)] * c[9];

#pragma unroll
    for (int a = 0; a < 3; ++a) {
        const int r = i + a - 1;
        if (r >= 0 && r < MM) {
            const float* row = yb + (size_t)r * MM;
            if (j > 0)      acc += c[a * 3 + 0] * row[j - 1];
            acc += c[a * 3 + 1] * row[j];
            if (j < MM - 1) acc += c[a * 3 + 2] * row[j + 1];
        }
    }

    yout[(size_t)b * MM * MM + (size_t)i * MM + j] = acc;
}

extern "C" void kernel_launch(void* const* d_in, const int* in_sizes, int n_in,
                              void* d_out, int out_size, void* d_ws, size_t ws_size,
                              hipStream_t stream) {
    // inputs: 0=x (unused), 1=pre (B,1,M,M), 2=f (B,1,N,N), 3=mu (1,),
    //         4=k1 (9), 5=k2 (9), 6=k3 (9)
    const float* pre = (const float*)d_in[1];
    const float* f   = (const float*)d_in[2];
    const float* mu  = (const float*)d_in[3];
    const float* k1  = (const float*)d_in[4];
    const float* k2  = (const float*)d_in[5];
    const float* k3  = (const float*)d_in[6];
    float* out = (float*)d_out;

    float* coef = (float*)d_ws;                       // 10 floats
    float* buf  = (float*)((char*)d_ws + 256);        // ping buffer, B*M*M floats

    coef_kernel<<<1, 64, 0, stream>>>(mu, k1, k2, k3, coef);

    dim3 block(256, 1, 1);
    dim3 grid((MM + 255) / 256, MM, BB);

    // 11 iterations; even t writes d_out, odd t writes ws buffer.
    // t=10 (last) is even -> final result lands in d_out.
    const float* in = pre;
    for (int t = 0; t < TOTAL_ITERS; ++t) {
        float* o = ((t & 1) == 0) ? out : buf;
        stencil_kernel<<<grid, block, 0, stream>>>(in, f, coef, o);
        in = o;
    }
}

// Round 2
// 334.839 us; speedup vs baseline: 1.9742x; 1.9742x over previous
//
#include <hip/hip_runtime.h>

#define NN 1024
#define MM 1022          // N-2 interior
#define BB 8
#define RR 8             // rows per thread (register blocking)
#define TOTAL_ITERS 11   // 1 explicit step + scan length 10

// coef[0..8] = mu*(k1+k2)/(mu*sum(k3)) ; coef[9] = H^2/(mu*sum(k3))
__global__ void coef_kernel(const float* __restrict__ mu,
                            const float* __restrict__ k1,
                            const float* __restrict__ k2,
                            const float* __restrict__ k3,
                            float* __restrict__ coef) {
    if (threadIdx.x == 0 && blockIdx.x == 0) {
        float m = mu[0];
        float s3 = 0.0f;
        for (int t = 0; t < 9; ++t) s3 += k3[t];
        float inv_d = 1.0f / (m * s3);
        for (int t = 0; t < 9; ++t) coef[t] = m * (k1[t] + k2[t]) * inv_d;
        const float h = 1.0f / (float)(NN - 1);
        coef[9] = h * h * inv_d;
    }
}

// Each thread: 4 consecutive columns (j0 = 4*tid), RR consecutive rows.
// 3-row register window (6 floats each) slides down; rows loaded once,
// reused for 3 output rows. float2 loads are 8B-aligned (even offsets,
// even strides everywhere).
__global__ __launch_bounds__(256) void stencil_kernel(
        const float* __restrict__ yin,
        const float* __restrict__ f,
        const float* __restrict__ coef,
        float* __restrict__ yout) {
    const int tid = threadIdx.x;
    const int j0  = tid * 4;                 // 0..1020
    const int i0  = blockIdx.x * RR;
    const int b   = blockIdx.y;
    const bool eL = (tid == 0);              // j0 == 0    : col -1 is Dirichlet 0
    const bool eR = (tid == 255);            // j0 == 1020 : only 2 valid cols

    const float* yb = yin + (size_t)b * MM * MM;
    const float* fb = f   + (size_t)b * NN * NN;
    float*       ob = yout + (size_t)b * MM * MM;

    float c[10];
#pragma unroll
    for (int t = 0; t < 10; ++t) c[t] = coef[t];

    float wP[6], wC[6], wN[6];

    auto loadwin = [&](int r, float* w) {
        if (r < 0 || r >= MM) {
#pragma unroll
            for (int k = 0; k < 6; ++k) w[k] = 0.0f;
            return;
        }
        const float* row = yb + (size_t)r * MM;
        if (eR) {
            float2 ab = *(const float2*)(row + j0);
            w[0] = row[j0 - 1];
            w[1] = ab.x; w[2] = ab.y;
            w[3] = 0.0f; w[4] = 0.0f; w[5] = 0.0f;
        } else {
            float2 ab = *(const float2*)(row + j0);
            float2 cd = *(const float2*)(row + j0 + 2);
            w[0] = eL ? 0.0f : row[j0 - 1];
            w[1] = ab.x; w[2] = ab.y;
            w[3] = cd.x; w[4] = cd.y;
            w[5] = row[j0 + 4];
        }
    };

    loadwin(i0 - 1, wP);
    loadwin(i0,     wC);

#pragma unroll
    for (int rr = 0; rr < RR; ++rr) {
        const int i = i0 + rr;
        if (i < MM) {
            loadwin(i + 1, wN);

            const float* frow = fb + (size_t)(i + 1) * NN;
            float fv[4];
            fv[0] = frow[j0 + 1];
            float2 fm = *(const float2*)(frow + j0 + 2);
            fv[1] = fm.x; fv[2] = fm.y;
            fv[3] = frow[j0 + 4];

            float acc[4];
#pragma unroll
            for (int k = 0; k < 4; ++k) acc[k] = c[9] * fv[k];
#pragma unroll
            for (int k = 0; k < 4; ++k) {
                acc[k] += c[0] * wP[k] + c[1] * wP[k + 1] + c[2] * wP[k + 2];
                acc[k] += c[3] * wC[k] + c[4] * wC[k + 1] + c[5] * wC[k + 2];
                acc[k] += c[6] * wN[k] + c[7] * wN[k + 1] + c[8] * wN[k + 2];
            }

            float* orow = ob + (size_t)i * MM;
            *(float2*)(orow + j0) = make_float2(acc[0], acc[1]);
            if (!eR) *(float2*)(orow + j0 + 2) = make_float2(acc[2], acc[3]);

#pragma unroll
            for (int k = 0; k < 6; ++k) { wP[k] = wC[k]; wC[k] = wN[k]; }
        }
    }
}

extern "C" void kernel_launch(void* const* d_in, const int* in_sizes, int n_in,
                              void* d_out, int out_size, void* d_ws, size_t ws_size,
                              hipStream_t stream) {
    // inputs: 0=x (unused), 1=pre (B,1,M,M), 2=f (B,1,N,N), 3=mu (1,),
    //         4=k1 (9), 5=k2 (9), 6=k3 (9)
    const float* pre = (const float*)d_in[1];
    const float* f   = (const float*)d_in[2];
    const float* mu  = (const float*)d_in[3];
    const float* k1  = (const float*)d_in[4];
    const float* k2  = (const float*)d_in[5];
    const float* k3  = (const float*)d_in[6];
    float* out = (float*)d_out;

    float* coef = (float*)d_ws;                       // 10 floats
    float* buf  = (float*)((char*)d_ws + 256);        // ping buffer, B*M*M floats

    coef_kernel<<<1, 64, 0, stream>>>(mu, k1, k2, k3, coef);

    dim3 block(256, 1, 1);
    dim3 grid((MM + RR - 1) / RR, BB, 1);             // 128 row-strips x 8 batch

    // 11 iterations; even t writes d_out, odd t writes ws buffer.
    // t=10 (last, even) -> final result lands in d_out.
    const float* in = pre;
    for (int t = 0; t < TOTAL_ITERS; ++t) {
        float* o = ((t & 1) == 0) ? out : buf;
        stencil_kernel<<<grid, block, 0, stream>>>(in, f, coef, o);
        in = o;
    }
}

// Round 3
// 334.707 us; speedup vs baseline: 1.9749x; 1.0004x over previous
//
#include <hip/hip_runtime.h>

#define NN 1024
#define MM 1022          // interior size
#define BB 8
#define RR 8             // rows per thread (register rolling window)
#define PS 1024          // padded stride AND padded row count (1024x1024/image)

// coef[0..8] = mu*(k1+k2)/(mu*sum(k3)) ; coef[9] = H^2/(mu*sum(k3))
__global__ void coef_kernel(const float* __restrict__ mu,
                            const float* __restrict__ k1,
                            const float* __restrict__ k2,
                            const float* __restrict__ k3,
                            float* __restrict__ coef) {
    if (threadIdx.x == 0 && blockIdx.x == 0) {
        float m = mu[0];
        float s3 = 0.0f;
        for (int t = 0; t < 9; ++t) s3 += k3[t];
        float inv_d = 1.0f / (m * s3);
        for (int t = 0; t < 9; ++t) coef[t] = m * (k1[t] + k2[t]) * inv_d;
        const float h = 1.0f / (float)(NN - 1);
        coef[9] = h * h * inv_d;
    }
}

// Padded layout Q[b][r][c]: r,c in [0,1024). Interior y[b][i][j] at r=i+1, c=j.
// Cols 1022,1023 and rows 0,1023 are zero pads. Rows are 4 KB aligned.
// prep: Q0 <- padded(pre); zero pad rows of Q1; forceP <- f_int * c9 (padded).
__global__ __launch_bounds__(256) void prep_kernel(
        const float* __restrict__ pre, const float* __restrict__ f,
        const float* __restrict__ coef,
        float* __restrict__ q0, float* __restrict__ q1,
        float* __restrict__ forceP) {
    const int tid = threadIdx.x;
    const int j0  = tid * 4;
    const int r   = blockIdx.x;          // 0..1023
    const int b   = blockIdx.y;
    float* q0r = q0 + ((size_t)b * PS + r) * PS;

    if (r == 0 || r == PS - 1) {         // zero pad rows in BOTH ping buffers
        float4 z = make_float4(0.f, 0.f, 0.f, 0.f);
        *(float4*)(q0r + j0) = z;
        float* q1r = q1 + ((size_t)b * PS + r) * PS;
        *(float4*)(q1r + j0) = z;
        return;
    }

    const int i = r - 1;                 // interior row
    const float* pr = pre + (size_t)b * MM * MM + (size_t)i * MM;
    float4 v;
    if (tid < 255) {
        float2 a  = *(const float2*)(pr + j0);
        float2 c2 = *(const float2*)(pr + j0 + 2);
        v = make_float4(a.x, a.y, c2.x, c2.y);
    } else {                             // cols 1020,1021 valid; 1022,1023 pad
        float2 a = *(const float2*)(pr + j0);
        v = make_float4(a.x, a.y, 0.f, 0.f);
    }
    *(float4*)(q0r + j0) = v;

    const float c9 = coef[9];
    const float* fr = f + ((size_t)b * NN + r) * NN;   // f row i+1 == r
    float4 fv;
    if (tid < 255) {
        float2 m = *(const float2*)(fr + j0 + 2);
        fv = make_float4(fr[j0 + 1] * c9, m.x * c9, m.y * c9, fr[j0 + 4] * c9);
    } else {
        fv = make_float4(fr[1021] * c9, fr[1022] * c9, 0.f, 0.f);
    }
    *(float4*)(forceP + ((size_t)b * PS + r) * PS + j0) = fv;
}

// One Jacobi step, padded -> padded. 5 aligned VMEM per 4 outputs.
__global__ __launch_bounds__(256) void stepP_kernel(
        const float* __restrict__ qin, const float* __restrict__ forceP,
        const float* __restrict__ coef, float* __restrict__ qout) {
    const int tid = threadIdx.x;
    const int j0  = tid * 4;
    const int r0  = blockIdx.x * RR + 1;     // first output padded row
    const int b   = blockIdx.y;
    const bool L = (tid == 0), R = (tid == 255);

    const float* qb = qin    + (size_t)b * PS * PS;
    const float* fb = forceP + (size_t)b * PS * PS;
    float*       ob = qout   + (size_t)b * PS * PS;

    float c[9];
#pragma unroll
    for (int t = 0; t < 9; ++t) c[t] = coef[t];

    float wP[6], wC[6], wN[6];
    auto ldrow = [&](int r, float* w) {
        const float* rp = qb + (size_t)r * PS;
        float4 v = *(const float4*)(rp + j0);
        w[0] = L ? 0.f : rp[j0 - 1];
        w[1] = v.x; w[2] = v.y; w[3] = v.z; w[4] = v.w;
        w[5] = R ? 0.f : rp[j0 + 4];
    };

    ldrow(r0 - 1, wP);
    ldrow(r0,     wC);

#pragma unroll
    for (int rr = 0; rr < RR; ++rr) {
        const int r = r0 + rr;
        if (r <= MM) {                        // block-uniform branch
            ldrow(r + 1, wN);
            float4 fv = *(const float4*)(fb + (size_t)r * PS + j0);
            float acc[4] = {fv.x, fv.y, fv.z, fv.w};
#pragma unroll
            for (int k = 0; k < 4; ++k) {
                acc[k] += c[0] * wP[k] + c[1] * wP[k + 1] + c[2] * wP[k + 2];
                acc[k] += c[3] * wC[k] + c[4] * wC[k + 1] + c[5] * wC[k + 2];
                acc[k] += c[6] * wN[k] + c[7] * wN[k + 1] + c[8] * wN[k + 2];
            }
            if (R) { acc[2] = 0.f; acc[3] = 0.f; }   // keep right pad cols zero
            *(float4*)(ob + (size_t)r * PS + j0) =
                make_float4(acc[0], acc[1], acc[2], acc[3]);
#pragma unroll
            for (int k = 0; k < 6; ++k) { wP[k] = wC[k]; wC[k] = wN[k]; }
        }
    }
}

// Last step: padded -> unpadded d_out (stride 1022).
__global__ __launch_bounds__(256) void finalP_kernel(
        const float* __restrict__ qin, const float* __restrict__ forceP,
        const float* __restrict__ coef, float* __restrict__ out) {
    const int tid = threadIdx.x;
    const int j0  = tid * 4;
    const int r0  = blockIdx.x * RR + 1;
    const int b   = blockIdx.y;
    const bool L = (tid == 0), R = (tid == 255);

    const float* qb = qin    + (size_t)b * PS * PS;
    const float* fb = forceP + (size_t)b * PS * PS;
    float*       ob = out    + (size_t)b * MM * MM;

    float c[9];
#pragma unroll
    for (int t = 0; t < 9; ++t) c[t] = coef[t];

    float wP[6], wC[6], wN[6];
    auto ldrow = [&](int r, float* w) {
        const float* rp = qb + (size_t)r * PS;
        float4 v = *(const float4*)(rp + j0);
        w[0] = L ? 0.f : rp[j0 - 1];
        w[1] = v.x; w[2] = v.y; w[3] = v.z; w[4] = v.w;
        w[5] = R ? 0.f : rp[j0 + 4];
    };

    ldrow(r0 - 1, wP);
    ldrow(r0,     wC);

#pragma unroll
    for (int rr = 0; rr < RR; ++rr) {
        const int r = r0 + rr;
        if (r <= MM) {
            ldrow(r + 1, wN);
            float4 fv = *(const float4*)(fb + (size_t)r * PS + j0);
            float acc[4] = {fv.x, fv.y, fv.z, fv.w};
#pragma unroll
            for (int k = 0; k < 4; ++k) {
                acc[k] += c[0] * wP[k] + c[1] * wP[k + 1] + c[2] * wP[k + 2];
                acc[k] += c[3] * wC[k] + c[4] * wC[k + 1] + c[5] * wC[k + 2];
                acc[k] += c[6] * wN[k] + c[7] * wN[k + 1] + c[8] * wN[k + 2];
            }
            float* orow = ob + (size_t)(r - 1) * MM;
            *(float2*)(orow + j0) = make_float2(acc[0], acc[1]);
            if (!R) *(float2*)(orow + j0 + 2) = make_float2(acc[2], acc[3]);
#pragma unroll
            for (int k = 0; k < 6; ++k) { wP[k] = wC[k]; wC[k] = wN[k]; }
        }
    }
}

// ---------- fallback (round-2 proven path, used if ws too small) ----------
__global__ __launch_bounds__(256) void stencil_kernel(
        const float* __restrict__ yin, const float* __restrict__ f,
        const float* __restrict__ coef, float* __restrict__ yout) {
    const int tid = threadIdx.x;
    const int j0  = tid * 4;
    const int i0  = blockIdx.x * RR;
    const int b   = blockIdx.y;
    const bool eL = (tid == 0), eR = (tid == 255);

    const float* yb = yin + (size_t)b * MM * MM;
    const float* fb = f   + (size_t)b * NN * NN;

    float c[10];
#pragma unroll
    for (int t = 0; t < 10; ++t) c[t] = coef[t];

    float wP[6], wC[6], wN[6];
    auto loadwin = [&](int r, float* w) {
        if (r < 0 || r >= MM) {
#pragma unroll
            for (int k = 0; k < 6; ++k) w[k] = 0.0f;
            return;
        }
        const float* row = yb + (size_t)r * MM;
        if (eR) {
            float2 ab = *(const float2*)(row + j0);
            w[0] = row[j0 - 1];
            w[1] = ab.x; w[2] = ab.y;
            w[3] = 0.0f; w[4] = 0.0f; w[5] = 0.0f;
        } else {
            float2 ab = *(const float2*)(row + j0);
            float2 cd = *(const float2*)(row + j0 + 2);
            w[0] = eL ? 0.0f : row[j0 - 1];
            w[1] = ab.x; w[2] = ab.y; w[3] = cd.x; w[4] = cd.y;
            w[5] = row[j0 + 4];
        }
    };

    loadwin(i0 - 1, wP);
    loadwin(i0,     wC);

#pragma unroll
    for (int rr = 0; rr < RR; ++rr) {
        const int i = i0 + rr;
        if (i < MM) {
            loadwin(i + 1, wN);
            const float* frow = fb + (size_t)(i + 1) * NN;
            float fv[4];
            fv[0] = frow[j0 + 1];
            float2 fm = *(const float2*)(frow + j0 + 2);
            fv[1] = fm.x; fv[2] = fm.y;
            fv[3] = frow[j0 + 4];
            float acc[4];
#pragma unroll
            for (int k = 0; k < 4; ++k) acc[k] = c[9] * fv[k];
#pragma unroll
            for (int k = 0; k < 4; ++k) {
                acc[k] += c[0] * wP[k] + c[1] * wP[k + 1] + c[2] * wP[k + 2];
                acc[k] += c[3] * wC[k] + c[4] * wC[k + 1] + c[5] * wC[k + 2];
                acc[k] += c[6] * wN[k] + c[7] * wN[k + 1] + c[8] * wN[k + 2];
            }
            float* orow = (yout + (size_t)b * MM * MM) + (size_t)i * MM;
            *(float2*)(orow + j0) = make_float2(acc[0], acc[1]);
            if (!eR) *(float2*)(orow + j0 + 2) = make_float2(acc[2], acc[3]);
#pragma unroll
            for (int k = 0; k < 6; ++k) { wP[k] = wC[k]; wC[k] = wN[k]; }
        }
    }
}

extern "C" void kernel_launch(void* const* d_in, const int* in_sizes, int n_in,
                              void* d_out, int out_size, void* d_ws, size_t ws_size,
                              hipStream_t stream) {
    const float* pre = (const float*)d_in[1];
    const float* f   = (const float*)d_in[2];
    const float* mu  = (const float*)d_in[3];
    const float* k1  = (const float*)d_in[4];
    const float* k2  = (const float*)d_in[5];
    const float* k3  = (const float*)d_in[6];
    float* out = (float*)d_out;

    float* coef = (float*)d_ws;
    const size_t QE = (size_t)BB * PS * PS;           // elements per padded buffer
    const size_t need = 256 + 3 * QE * sizeof(float); // ~100.7 MB

    coef_kernel<<<1, 64, 0, stream>>>(mu, k1, k2, k3, coef);

    if (ws_size >= need) {
        float* q0 = (float*)((char*)d_ws + 256);
        float* q1 = q0 + QE;
        float* fp = q1 + QE;

        prep_kernel<<<dim3(PS, BB), 256, 0, stream>>>(pre, f, coef, q0, q1, fp);

        dim3 grid((MM + RR - 1) / RR, BB);
        const float* in = q0;
        float* ob = q1;
        for (int s = 0; s < 10; ++s) {                // 10 padded steps
            stepP_kernel<<<grid, 256, 0, stream>>>(in, fp, coef, ob);
            float* t = (float*)in; in = ob; ob = t;
        }
        // after even number of swaps, in == q0
        finalP_kernel<<<grid, 256, 0, stream>>>(in, fp, coef, out);
    } else {
        // fallback: round-2 proven path (needs ~33.6 MB ws)
        float* buf = (float*)((char*)d_ws + 256);
        dim3 grid((MM + RR - 1) / RR, BB);
        const float* in = pre;
        for (int t = 0; t < 11; ++t) {
            float* o = ((t & 1) == 0) ? out : buf;
            stencil_kernel<<<grid, 256, 0, stream>>>(in, f, coef, o);
            in = o;
        }
    }
}

// Round 4
// 332.173 us; speedup vs baseline: 1.9900x; 1.0076x over previous
//
#include <hip/hip_runtime.h>

#define NN 1024
#define MM 1022          // interior size
#define PS 1024          // padded col stride for ws buffers (16B-aligned rows)
#define BB 8
#define RB 32            // output rows per block strip (fused kernels)
#define RR 8             // rows/thread in fallback kernel

// coef[0..8] = mu*(k1+k2)/(mu*sum(k3)) ; coef[9] = H^2/(mu*sum(k3))
__global__ void coef_kernel(const float* __restrict__ mu,
                            const float* __restrict__ k1,
                            const float* __restrict__ k2,
                            const float* __restrict__ k3,
                            float* __restrict__ coef) {
    if (threadIdx.x == 0 && blockIdx.x == 0) {
        float m = mu[0];
        float s3 = 0.0f;
        for (int t = 0; t < 9; ++t) s3 += k3[t];
        float inv_d = 1.0f / (m * s3);
        for (int t = 0; t < 9; ++t) coef[t] = m * (k1[t] + k2[t]) * inv_d;
        const float h = 1.0f / (float)(NN - 1);
        coef[9] = h * h * inv_d;
    }
}

// forceP[b][x][j] = c9 * f[b][0][x+1][j+1] for j<MM; 0 for j=1022,1023.
// Layout: MM rows x PS stride per batch (rows 16B-aligned -> float4 reads).
__global__ __launch_bounds__(256) void force_kernel(
        const float* __restrict__ f, const float* __restrict__ coef,
        float* __restrict__ forceP) {
    const int tid = threadIdx.x;
    const int j0  = tid * 4;
    const int x   = blockIdx.x;          // 0..MM-1
    const int b   = blockIdx.y;
    const float c9 = coef[9];
    const float* fr = f + ((size_t)b * NN + (x + 1)) * NN + 1; // fr[j] = f[x+1][j+1]
    float4 v;
    if (tid < 255) {
        // element offsets: fr+j0 is odd-aligned; fr+j0+1 is even (8B-aligned)
        float2 m2 = *(const float2*)(fr + j0 + 1);
        v = make_float4(fr[j0] * c9, m2.x * c9, m2.y * c9, fr[j0 + 3] * c9);
    } else {
        v = make_float4(fr[j0] * c9, fr[j0 + 1] * c9, 0.f, 0.f);
    }
    *(float4*)(forceP + ((size_t)b * MM + x) * PS + j0) = v;
}

template <bool IN_PAD>
__device__ inline void load_y_row(const float* __restrict__ ybase, int x,
                                  int j0, int tid, float* o) {
    if (x < 0 || x >= MM) { o[0] = o[1] = o[2] = o[3] = 0.f; return; }
    if constexpr (IN_PAD) {
        const float4 v = *(const float4*)(ybase + (size_t)x * PS + j0);
        o[0] = v.x; o[1] = v.y; o[2] = v.z; o[3] = v.w;
    } else {
        const float* r = ybase + (size_t)x * MM + j0;
        if (tid < 255) {
            float2 a = *(const float2*)r;
            float2 c2 = *(const float2*)(r + 2);
            o[0] = a.x; o[1] = a.y; o[2] = c2.x; o[3] = c2.y;
        } else {
            float2 a = *(const float2*)r;
            o[0] = a.x; o[1] = a.y; o[2] = 0.f; o[3] = 0.f;
        }
    }
}

// Fused T-step wavefront pipeline.
// Level 0 stages input rows into ring[0]; level t (1..T) computes one Jacobi
// step from level t-1. Skew-2 scheduling: level t at iter s handles row
// x_t = i0 - T + s - 2t, ingesting the row level t-1 produced at iter s-1.
// => depth-2 rings, ONE barrier per iteration.
template <int T, bool IN_PAD, bool OUT_PAD>
__global__ __launch_bounds__(256, 1) void fused_kernel(
        const float* __restrict__ yin, const float* __restrict__ forceP,
        const float* __restrict__ coef, float* __restrict__ yout) {
    const int tid = threadIdx.x;
    const int j0  = tid * 4;
    const int i0  = blockIdx.x * RB;
    const int b   = blockIdx.y;
    const bool L = (tid == 0), R = (tid == 255);
    const int S = RB + 3 * T;

    __shared__ float ring[T][2][PS];

    float c[9];
#pragma unroll
    for (int k = 0; k < 9; ++k) c[k] = coef[k];

    const float* yB = yin + (size_t)b * MM * (IN_PAD ? PS : MM);
    const float* fB = forceP + (size_t)b * MM * PS;

    float W[T][3][6];     // per-level 3-row x 6-col register window
#pragma unroll
    for (int t = 0; t < T; ++t)
#pragma unroll
        for (int a = 0; a < 3; ++a)
#pragma unroll
            for (int k = 0; k < 6; ++k) W[t][a][k] = 0.f;

    float fpf[T][4];      // force prefetch (row for NEXT iter's compute)
#pragma unroll
    for (int t = 0; t < T; ++t)
#pragma unroll
        for (int k = 0; k < 4; ++k) fpf[t][k] = 0.f;

    float ypf[4];         // y-row prefetch (staged NEXT... staged this iter)
    load_y_row<IN_PAD>(yB, i0 - T, j0, tid, ypf);   // row for s=0

    for (int s = 0; s < S; ++s) {
        const int p = s & 1, q = p ^ 1;
        const int x0 = i0 - T + s;   // level-0 row staged this iter

        // ---- level 0: stage prefetched row into ring ----
        if (s <= RB + 2 * T - 1) {
            *(float4*)(&ring[0][p][j0]) =
                make_float4(ypf[0], ypf[1], ypf[2], ypf[3]);
        }

        // ---- levels 1..T: shift window, ingest, compute ----
#pragma unroll
        for (int t = 1; t <= T; ++t) {
            // shift window down
#pragma unroll
            for (int k = 0; k < 6; ++k) {
                W[t - 1][0][k] = W[t - 1][1][k];
                W[t - 1][1][k] = W[t - 1][2][k];
            }
            // ingest row xin = x_t + 1 (produced by level t-1 at iter s-1)
            const int xin = x0 - 2 * t + 1;
            bool prod;
            if (t == 1) prod = (s - 1 >= 0) && (s - 1 <= RB + 2 * T - 1);
            else        prod = (s - 1 >= 3 * (t - 1)) &&
                               (s - 1 <= RB - 1 + 2 * T + (t - 1));
            if (prod && xin >= 0 && xin < MM) {
                const float* slot = &ring[t - 1][q][0];
                float4 v = *(const float4*)(slot + j0);
                W[t - 1][2][0] = L ? 0.f : slot[j0 - 1];
                W[t - 1][2][1] = v.x; W[t - 1][2][2] = v.y;
                W[t - 1][2][3] = v.z; W[t - 1][2][4] = v.w;
                W[t - 1][2][5] = R ? 0.f : slot[j0 + 4];
            } else {
#pragma unroll
                for (int k = 0; k < 6; ++k) W[t - 1][2][k] = 0.f;
            }

            // compute row x_t
            const int xt = x0 - 2 * t;
            if (s >= 3 * t && s <= RB - 1 + 2 * T + t && xt >= 0 && xt < MM) {
                float acc[4];
#pragma unroll
                for (int k = 0; k < 4; ++k) acc[k] = fpf[t - 1][k];
#pragma unroll
                for (int a = 0; a < 3; ++a) {
                    const float* w = W[t - 1][a];
#pragma unroll
                    for (int k = 0; k < 4; ++k)
                        acc[k] += c[3 * a + 0] * w[k] +
                                  c[3 * a + 1] * w[k + 1] +
                                  c[3 * a + 2] * w[k + 2];
                }
                if (R) { acc[2] = 0.f; acc[3] = 0.f; }   // keep pad cols zero
                if (t < T) {
                    *(float4*)(&ring[t][p][j0]) =
                        make_float4(acc[0], acc[1], acc[2], acc[3]);
                } else if (OUT_PAD) {
                    *(float4*)(yout + ((size_t)b * MM + xt) * PS + j0) =
                        make_float4(acc[0], acc[1], acc[2], acc[3]);
                } else {
                    float* orow = yout + (size_t)b * MM * MM +
                                  (size_t)xt * MM + j0;
                    *(float2*)orow = make_float2(acc[0], acc[1]);
                    if (!R) *(float2*)(orow + 2) = make_float2(acc[2], acc[3]);
                }
            }
        }

        // ---- prefetches for next iteration ----
        if (s + 1 <= RB + 2 * T - 1)
            load_y_row<IN_PAD>(yB, x0 + 1, j0, tid, ypf);
#pragma unroll
        for (int t = 1; t <= T; ++t) {
            const int xc = x0 + 1 - 2 * t;      // row level t computes at s+1
            if ((s + 1) >= 3 * t && (s + 1) <= RB - 1 + 2 * T + t &&
                xc >= 0 && xc < MM) {
                float4 v = *(const float4*)(fB + (size_t)xc * PS + j0);
                fpf[t - 1][0] = v.x; fpf[t - 1][1] = v.y;
                fpf[t - 1][2] = v.z; fpf[t - 1][3] = v.w;
            }
        }

        __syncthreads();
    }
}

// ---------- fallback (round-2 proven path, used if ws too small) ----------
__global__ __launch_bounds__(256) void stencil_kernel(
        const float* __restrict__ yin, const float* __restrict__ f,
        const float* __restrict__ coef, float* __restrict__ yout) {
    const int tid = threadIdx.x;
    const int j0  = tid * 4;
    const int i0  = blockIdx.x * RR;
    const int b   = blockIdx.y;
    const bool eL = (tid == 0), eR = (tid == 255);

    const float* yb = yin + (size_t)b * MM * MM;
    const float* fb = f   + (size_t)b * NN * NN;

    float c[10];
#pragma unroll
    for (int t = 0; t < 10; ++t) c[t] = coef[t];

    float wP[6], wC[6], wN[6];
    auto loadwin = [&](int r, float* w) {
        if (r < 0 || r >= MM) {
#pragma unroll
            for (int k = 0; k < 6; ++k) w[k] = 0.0f;
            return;
        }
        const float* row = yb + (size_t)r * MM;
        if (eR) {
            float2 ab = *(const float2*)(row + j0);
            w[0] = row[j0 - 1];
            w[1] = ab.x; w[2] = ab.y;
            w[3] = 0.0f; w[4] = 0.0f; w[5] = 0.0f;
        } else {
            float2 ab = *(const float2*)(row + j0);
            float2 cd = *(const float2*)(row + j0 + 2);
            w[0] = eL ? 0.0f : row[j0 - 1];
            w[1] = ab.x; w[2] = ab.y; w[3] = cd.x; w[4] = cd.y;
            w[5] = row[j0 + 4];
        }
    };

    loadwin(i0 - 1, wP);
    loadwin(i0,     wC);

#pragma unroll
    for (int rr = 0; rr < RR; ++rr) {
        const int i = i0 + rr;
        if (i < MM) {
            loadwin(i + 1, wN);
            const float* frow = fb + (size_t)(i + 1) * NN;
            float fv[4];
            fv[0] = frow[j0 + 1];
            float2 fm = *(const float2*)(frow + j0 + 2);
            fv[1] = fm.x; fv[2] = fm.y;
            fv[3] = frow[j0 + 4];
            float acc[4];
#pragma unroll
            for (int k = 0; k < 4; ++k) acc[k] = c[9] * fv[k];
#pragma unroll
            for (int k = 0; k < 4; ++k) {
                acc[k] += c[0] * wP[k] + c[1] * wP[k + 1] + c[2] * wP[k + 2];
                acc[k] += c[3] * wC[k] + c[4] * wC[k + 1] + c[5] * wC[k + 2];
                acc[k] += c[6] * wN[k] + c[7] * wN[k + 1] + c[8] * wN[k + 2];
            }
            float* orow = (yout + (size_t)b * MM * MM) + (size_t)i * MM + j0;
            *(float2*)orow = make_float2(acc[0], acc[1]);
            if (!eR) *(float2*)(orow + 2) = make_float2(acc[2], acc[3]);
#pragma unroll
            for (int k = 0; k < 6; ++k) { wP[k] = wC[k]; wC[k] = wN[k]; }
        }
    }
}

extern "C" void kernel_launch(void* const* d_in, const int* in_sizes, int n_in,
                              void* d_out, int out_size, void* d_ws, size_t ws_size,
                              hipStream_t stream) {
    const float* pre = (const float*)d_in[1];
    const float* f   = (const float*)d_in[2];
    const float* mu  = (const float*)d_in[3];
    const float* k1  = (const float*)d_in[4];
    const float* k2  = (const float*)d_in[5];
    const float* k3  = (const float*)d_in[6];
    float* out = (float*)d_out;

    float* coef = (float*)d_ws;
    const size_t QE = (size_t)BB * MM * PS;               // elems per padded buf
    const size_t need = 256 + 2 * QE * sizeof(float);     // ~67 MB

    coef_kernel<<<1, 64, 0, stream>>>(mu, k1, k2, k3, coef);

    if (ws_size >= need) {
        float* forceP = (float*)((char*)d_ws + 256);
        float* q0     = forceP + QE;

        force_kernel<<<dim3(MM, BB), 256, 0, stream>>>(f, coef, forceP);

        dim3 grid((MM + RB - 1) / RB, BB);   // 32 x 8 = 256 blocks
        // 11 steps = 6 + 5
        fused_kernel<6, false, true><<<grid, 256, 0, stream>>>(pre, forceP, coef, q0);
        fused_kernel<5, true, false><<<grid, 256, 0, stream>>>(q0, forceP, coef, out);
    } else {
        // fallback: round-2 proven path (needs ~33.6 MB ws)
        float* buf = (float*)((char*)d_ws + 256);
        dim3 grid((MM + RR - 1) / RR, BB);
        const float* in = pre;
        for (int t = 0; t < 11; ++t) {
            float* o = ((t & 1) == 0) ? out : buf;
            stencil_kernel<<<grid, 256, 0, stream>>>(in, f, coef, o);
            in = o;
        }
    }
}

// Round 5
// 283.311 us; speedup vs baseline: 2.3332x; 1.1725x over previous
//
#include <hip/hip_runtime.h>

#define NN 1024
#define MM 1022          // interior size
#define PS 1024          // padded col stride for ws q0 buffer
#define BB 8
#define TI 64            // trapezoid tile input size
#define SL 68            // LDS row stride: 64 data + 4 guard (16B-aligned rows)
#define RRF 8            // fallback rows/thread

// coef[0..8] = mu*(k1+k2)/(mu*sum(k3)) ; coef[9] = H^2/(mu*sum(k3))
__global__ void coef_kernel(const float* __restrict__ mu,
                            const float* __restrict__ k1,
                            const float* __restrict__ k2,
                            const float* __restrict__ k3,
                            float* __restrict__ coef) {
    if (threadIdx.x == 0 && blockIdx.x == 0) {
        float m = mu[0];
        float s3 = 0.0f;
        for (int t = 0; t < 9; ++t) s3 += k3[t];
        float inv_d = 1.0f / (m * s3);
        for (int t = 0; t < 9; ++t) coef[t] = m * (k1[t] + k2[t]) * inv_d;
        const float h = 1.0f / (float)(NN - 1);
        coef[9] = h * h * inv_d;
    }
}

// Overlapped-tile fused T-step Jacobi. Tile input TI x TI in LDS (double
// buffered), T steps with one barrier each, write central OUT^2.
// Validity pyramid: cell at tile-edge-distance d holds step-s value iff d>=s;
// edge cells go stale (finite) and are never read by valid cells.
// Global Dirichlet: out-of-image cells masked to 0 every step (mk).
template <int T, bool IN_PAD, bool OUT_PAD>
__global__ __launch_bounds__(256) void trap_kernel(
        const float* __restrict__ yin, const float* __restrict__ f,
        const float* __restrict__ coef, float* __restrict__ yout) {
    constexpr int OUT = TI - 2 * T;
    __shared__ float buf[2][TI * SL];

    const int t  = threadIdx.x;
    const int b  = blockIdx.z;
    const int o0r = blockIdx.y * OUT - T;   // tile origin, global interior coords
    const int o0c = blockIdx.x * OUT - T;

    float c[10];
#pragma unroll
    for (int k = 0; k < 10; ++k) c[k] = coef[k];

    // ---- load phase (lane-contiguous cols -> coalesced) ----
    {
        const int lcol = t & 63;
        const int w    = t >> 6;            // 0..3
        const int gc   = o0c + lcol;
        const bool cok = (gc >= 0) && (gc < MM);
#pragma unroll
        for (int e = 0; e < 16; ++e) {
            const int lrow = e * 4 + w;
            const int gr = o0r + lrow;
            float v = 0.f;
            if (cok && gr >= 0 && gr < MM) {
                v = IN_PAD ? yin[((size_t)b * MM + gr) * PS + gc]
                           : yin[((size_t)b * MM + gr) * MM + gc];
            }
            buf[0][lrow * SL + lcol] = v;
        }
        // zero guard cols (idx 64..67) in both buffers
        const int grow = t >> 2, gcol = 64 + (t & 3);
        buf[0][grow * SL + gcol] = 0.f;
        buf[1][grow * SL + gcol] = 0.f;
    }

    // ---- per-thread force + Dirichlet mask registers (compute layout) ----
    const int cg = t & 15, rg = t >> 4;
    const int lc0 = cg * 4, lr0 = rg * 4;
    float fr[4][4], mk[4][4];
#pragma unroll
    for (int r = 0; r < 4; ++r) {
        const int gr = o0r + lr0 + r;
#pragma unroll
        for (int cc = 0; cc < 4; ++cc) {
            const int gc = o0c + lc0 + cc;
            const bool ok = (gr >= 0) && (gr < MM) && (gc >= 0) && (gc < MM);
            mk[r][cc] = ok ? 1.f : 0.f;
            fr[r][cc] = ok ? c[9] * f[((size_t)b * NN + (gr + 1)) * NN + (gc + 1)]
                           : 0.f;
        }
    }
    __syncthreads();

    // ---- T fused steps, one barrier each ----
#pragma unroll
    for (int s = 1; s <= T; ++s) {
        const float* src = buf[(s - 1) & 1];
        float*       dst = buf[s & 1];

        float w0[6], w1[6], w2[6];
        auto rd = [&](int row, float* wv) {
            const float* rp = src + row * SL;
            wv[0] = rp[(cg == 0) ? 64 : lc0 - 1];   // guard==0 at tile edge
            float4 v = *(const float4*)(rp + lc0);
            wv[1] = v.x; wv[2] = v.y; wv[3] = v.z; wv[4] = v.w;
            wv[5] = rp[lc0 + 4];                    // cg==15 hits guard (0)
        };
        rd((lr0 == 0) ? 0 : lr0 - 1, w0);
        rd(lr0, w1);

#pragma unroll
        for (int r = 0; r < 4; ++r) {
            const int lrow = lr0 + r;
            rd(min(lrow + 1, TI - 1), w2);
            if (lrow >= 1 && lrow <= TI - 2) {
                float acc[4];
#pragma unroll
                for (int cc = 0; cc < 4; ++cc) {
                    float s0 = c[0] * w0[cc] + c[1] * w0[cc + 1] + c[2] * w0[cc + 2]
                             + c[3] * w1[cc] + c[4] * w1[cc + 1] + c[5] * w1[cc + 2]
                             + c[6] * w2[cc] + c[7] * w2[cc + 1] + c[8] * w2[cc + 2];
                    acc[cc] = mk[r][cc] * s0 + fr[r][cc];   // Dirichlet mask
                }
                *(float4*)(dst + lrow * SL + lc0) =
                    make_float4(acc[0], acc[1], acc[2], acc[3]);
            }
#pragma unroll
            for (int k = 0; k < 6; ++k) { w0[k] = w1[k]; w1[k] = w2[k]; }
        }
        __syncthreads();
    }

    // ---- store central OUT^2 (lane-contiguous cols -> coalesced) ----
    {
        const float* res = buf[T & 1];
        const int lcol = t & 63;
        const int w    = t >> 6;
        const int oc   = o0c + lcol;
        if (lcol >= T && lcol < T + OUT && oc < MM) {
#pragma unroll
            for (int e = 0; e < 16; ++e) {
                const int lrow = e * 4 + w;
                const int orow = o0r + lrow;
                if (lrow >= T && lrow < T + OUT && orow < MM) {
                    const float v = res[lrow * SL + lcol];
                    if (OUT_PAD) yout[((size_t)b * MM + orow) * PS + oc] = v;
                    else         yout[((size_t)b * MM + orow) * MM + oc] = v;
                }
            }
        }
    }
}

// ---------- fallback (round-2 proven path, used if ws too small) ----------
__global__ __launch_bounds__(256) void stencil_kernel(
        const float* __restrict__ yin, const float* __restrict__ f,
        const float* __restrict__ coef, float* __restrict__ yout) {
    const int tid = threadIdx.x;
    const int j0  = tid * 4;
    const int i0  = blockIdx.x * RRF;
    const int b   = blockIdx.y;
    const bool eL = (tid == 0), eR = (tid == 255);

    const float* yb = yin + (size_t)b * MM * MM;
    const float* fb = f   + (size_t)b * NN * NN;

    float c[10];
#pragma unroll
    for (int t = 0; t < 10; ++t) c[t] = coef[t];

    float wP[6], wC[6], wN[6];
    auto loadwin = [&](int r, float* w) {
        if (r < 0 || r >= MM) {
#pragma unroll
            for (int k = 0; k < 6; ++k) w[k] = 0.0f;
            return;
        }
        const float* row = yb + (size_t)r * MM;
        if (eR) {
            float2 ab = *(const float2*)(row + j0);
            w[0] = row[j0 - 1];
            w[1] = ab.x; w[2] = ab.y;
            w[3] = 0.0f; w[4] = 0.0f; w[5] = 0.0f;
        } else {
            float2 ab = *(const float2*)(row + j0);
            float2 cd = *(const float2*)(row + j0 + 2);
            w[0] = eL ? 0.0f : row[j0 - 1];
            w[1] = ab.x; w[2] = ab.y; w[3] = cd.x; w[4] = cd.y;
            w[5] = row[j0 + 4];
        }
    };

    loadwin(i0 - 1, wP);
    loadwin(i0,     wC);

#pragma unroll
    for (int rr = 0; rr < RRF; ++rr) {
        const int i = i0 + rr;
        if (i < MM) {
            loadwin(i + 1, wN);
            const float* frow = fb + (size_t)(i + 1) * NN;
            float fv[4];
            fv[0] = frow[j0 + 1];
            float2 fm = *(const float2*)(frow + j0 + 2);
            fv[1] = fm.x; fv[2] = fm.y;
            fv[3] = frow[j0 + 4];
            float acc[4];
#pragma unroll
            for (int k = 0; k < 4; ++k) acc[k] = c[9] * fv[k];
#pragma unroll
            for (int k = 0; k < 4; ++k) {
                acc[k] += c[0] * wP[k] + c[1] * wP[k + 1] + c[2] * wP[k + 2];
                acc[k] += c[3] * wC[k] + c[4] * wC[k + 1] + c[5] * wC[k + 2];
                acc[k] += c[6] * wN[k] + c[7] * wN[k + 1] + c[8] * wN[k + 2];
            }
            float* orow = (yout + (size_t)b * MM * MM) + (size_t)i * MM + j0;
            *(float2*)orow = make_float2(acc[0], acc[1]);
            if (!eR) *(float2*)(orow + 2) = make_float2(acc[2], acc[3]);
#pragma unroll
            for (int k = 0; k < 6; ++k) { wP[k] = wC[k]; wC[k] = wN[k]; }
        }
    }
}

extern "C" void kernel_launch(void* const* d_in, const int* in_sizes, int n_in,
                              void* d_out, int out_size, void* d_ws, size_t ws_size,
                              hipStream_t stream) {
    const float* pre = (const float*)d_in[1];
    const float* f   = (const float*)d_in[2];
    const float* mu  = (const float*)d_in[3];
    const float* k1  = (const float*)d_in[4];
    const float* k2  = (const float*)d_in[5];
    const float* k3  = (const float*)d_in[6];
    float* out = (float*)d_out;

    float* coef = (float*)d_ws;
    const size_t QE = (size_t)BB * MM * PS;               // intermediate buffer
    const size_t need = 256 + QE * sizeof(float);         // ~33.5 MB

    coef_kernel<<<1, 64, 0, stream>>>(mu, k1, k2, k3, coef);

    if (ws_size >= need) {
        float* q0 = (float*)((char*)d_ws + 256);

        // pass 1: T=6, OUT=52 -> q0 holds y_6 (padded-stride layout)
        {
            constexpr int T = 6, OUTW = TI - 2 * T;       // 52
            const int nt = (MM + OUTW - 1) / OUTW;        // 20
            trap_kernel<T, false, true>
                <<<dim3(nt, nt, BB), 256, 0, stream>>>(pre, f, coef, q0);
        }
        // pass 2: T=5, OUT=54 -> out holds y_11
        {
            constexpr int T = 5, OUTW = TI - 2 * T;       // 54
            const int nt = (MM + OUTW - 1) / OUTW;        // 19
            trap_kernel<T, true, false>
                <<<dim3(nt, nt, BB), 256, 0, stream>>>(q0, f, coef, out);
        }
    } else {
        // fallback: round-2 proven path
        float* buf = (float*)((char*)d_ws + 256);
        dim3 grid((MM + RRF - 1) / RRF, BB);
        const float* in = pre;
        for (int t = 0; t < 11; ++t) {
            float* o = ((t & 1) == 0) ? out : buf;
            stencil_kernel<<<grid, 256, 0, stream>>>(in, f, coef, o);
            in = o;
        }
    }
}